// Round 2
// baseline (470.802 us; speedup 1.0000x reference)
//
#include <hip/hip_runtime.h>

// B=4096, ID=2048, OD=1024. 4-level pyramidal LSTM, f32 I/O, bf16 MFMA GEMMs.
// Per level l (S segments, H=OD/S, Kx=ID/S):
//   g[m,4H] = x[m,:]@Wih^T + h_in[m,:]@Whh^T  (m=b*S+s; biases added in gate kernel)
//   i,f,gg,o = split(g); c2=sig(f)*c_in+sig(i)*tanh(gg); h2=sig(o)*tanh(c2)
//   blend: conv1d(k=3,pad=1) over pair-merged rows, then row softmax -> hb(bf16), cb(f32)

typedef __bf16 bf16x8 __attribute__((ext_vector_type(8)));
typedef float f32x4 __attribute__((ext_vector_type(4)));
typedef unsigned short u16x4 __attribute__((ext_vector_type(4)));

__device__ __forceinline__ unsigned short f2bf(float f) {
    union { float f; unsigned int i; } v; v.f = f;
    unsigned int r = v.i + 0x7fffu + ((v.i >> 16) & 1u);
    return (unsigned short)(r >> 16);
}
__device__ __forceinline__ float sigm(float x) { return 1.f / (1.f + __expf(-x)); }
__device__ __forceinline__ float tanh_(float x) { float e = __expf(2.f * x); return 1.f - 2.f / (e + 1.f); }

// ---------------- f32 -> bf16 convert (vectorized, grid-stride)
__global__ __launch_bounds__(256) void cvt_f32_bf16(
    const float* __restrict__ src, unsigned short* __restrict__ dst, long n4)
{
    const long stride = (long)gridDim.x * blockDim.x;
    for (long i = (long)blockIdx.x * blockDim.x + threadIdx.x; i < n4; i += stride) {
        const float4 v = ((const float4*)src)[i];
        u16x4 o;
        o.x = f2bf(v.x); o.y = f2bf(v.y); o.z = f2bf(v.z); o.w = f2bf(v.w);
        ((u16x4*)dst)[i] = o;
    }
}

// ---------------- GEMM: G[M,N] = A0[M,K0]@W0[N,K0]^T + A1[M,K1]@W1[N,K1]^T (f32 out)
// m97 structure: 128x128 tile, BK=64, 4 waves (2x2 of 64x64), global_load_lds w=16.
__global__ __launch_bounds__(256) void gemm_bt(
    const unsigned short* __restrict__ A0, const unsigned short* __restrict__ W0, int K0,
    const unsigned short* __restrict__ A1, const unsigned short* __restrict__ W1, int K1,
    float* __restrict__ G, int N)
{
    __shared__ unsigned short As[128 * 64];
    __shared__ unsigned short Bs[128 * 64];
    const int t = threadIdx.x;
    const int w = t >> 6, l = t & 63;
    const int m0 = blockIdx.x * 128, n0 = blockIdx.y * 128;
    const int wr = (w >> 1) * 64, wc = (w & 1) * 64;   // wave's 64x64 quadrant
    const int row8 = l >> 3, colel = (l & 7) * 8;      // staging: lane -> (row-in-8, col*8)
    const int lr = l & 15, lk = (l >> 4) * 8;          // mfma fragment indices

    f32x4 acc[4][4];
#pragma unroll
    for (int i = 0; i < 4; ++i)
#pragma unroll
        for (int j = 0; j < 4; ++j) acc[i][j] = (f32x4){0.f, 0.f, 0.f, 0.f};

    const int nk0 = K0 >> 6, nkt = (K0 + K1) >> 6;
    for (int kt = 0; kt < nkt; ++kt) {
        const unsigned short *Ap, *Wp; int ld, k0;
        if (kt < nk0) { Ap = A0; Wp = W0; ld = K0; k0 = kt << 6; }
        else          { Ap = A1; Wp = W1; ld = K1; k0 = (kt - nk0) << 6; }
#pragma unroll
        for (int r = 0; r < 4; ++r) {
            const int chunk = w * 4 + r;               // 16 chunks of 8 rows x 64 cols
            const unsigned short* ga = Ap + (size_t)(m0 + chunk * 8 + row8) * ld + (k0 + colel);
            const unsigned short* gb = Wp + (size_t)(n0 + chunk * 8 + row8) * ld + (k0 + colel);
            __builtin_amdgcn_global_load_lds((const __attribute__((address_space(1))) void*)ga,
                (__attribute__((address_space(3))) void*)(&As[chunk * 512]), 16, 0, 0);
            __builtin_amdgcn_global_load_lds((const __attribute__((address_space(1))) void*)gb,
                (__attribute__((address_space(3))) void*)(&Bs[chunk * 512]), 16, 0, 0);
        }
        __syncthreads();   // compiler drains vmcnt before s_barrier -> tiles ready
#pragma unroll
        for (int ks = 0; ks < 2; ++ks) {
            bf16x8 af[4], bfr[4];
#pragma unroll
            for (int mi = 0; mi < 4; ++mi)
                af[mi] = *(const bf16x8*)&As[(wr + mi * 16 + lr) * 64 + ks * 32 + lk];
#pragma unroll
            for (int ni = 0; ni < 4; ++ni)
                bfr[ni] = *(const bf16x8*)&Bs[(wc + ni * 16 + lr) * 64 + ks * 32 + lk];
#pragma unroll
            for (int mi = 0; mi < 4; ++mi)
#pragma unroll
                for (int ni = 0; ni < 4; ++ni)
                    acc[mi][ni] = __builtin_amdgcn_mfma_f32_16x16x32_bf16(
                        af[mi], bfr[ni], acc[mi][ni], 0, 0, 0);
        }
        __syncthreads();
    }
    // epilogue: C/D layout col=lane&15, row=(lane>>4)*4+reg  [m89-verified]
#pragma unroll
    for (int mi = 0; mi < 4; ++mi)
#pragma unroll
        for (int ni = 0; ni < 4; ++ni)
#pragma unroll
            for (int j = 0; j < 4; ++j) {
                const int grow = m0 + wr + mi * 16 + (l >> 4) * 4 + j;
                const int gcol = n0 + wc + ni * 16 + (l & 15);
                G[(size_t)grow * N + gcol] = acc[mi][ni][j];
            }
}

// ---------------- gate kernel: consume g (f32), produce h,c (f32)
template<bool HAS_CIN, bool LAST>
__global__ __launch_bounds__(256) void gate_kernel(
    const float* __restrict__ G,
    const float* __restrict__ bih, const float* __restrict__ bhh,
    const float* __restrict__ Cin,
    float* __restrict__ Hout, float* __restrict__ Cout,
    int logH, long total)
{
    const int H = 1 << logH;
    const long stride = (long)gridDim.x * blockDim.x;
    for (long idx = (long)blockIdx.x * blockDim.x + threadIdx.x; idx < total; idx += stride) {
        const long m = idx >> logH;
        const int n = (int)(idx & (H - 1));
        const float* g = G + (m << (logH + 2));
        const float gi = g[n]         + bih[n]         + bhh[n];
        const float gf = g[n + H]     + bih[n + H]     + bhh[n + H];
        const float gg = g[n + 2 * H] + bih[n + 2 * H] + bhh[n + 2 * H];
        const float go = g[n + 3 * H] + bih[n + 3 * H] + bhh[n + 3 * H];
        float c2 = sigm(gi) * tanh_(gg);
        if (HAS_CIN) c2 += sigm(gf) * Cin[idx];
        const float h2 = sigm(go) * tanh_(c2);
        Hout[idx] = h2;
        if (!LAST) Cout[idx] = c2;
    }
}

// ---------------- conv1d(k=3,pad=1) + row softmax; one block per row of length L
template<int L, bool OUT_BF16>
__global__ __launch_bounds__(256) void conv_softmax(
    const float* __restrict__ X, const float* __restrict__ w3,
    float* __restrict__ Yf, unsigned short* __restrict__ Yb)
{
    __shared__ float xs[L + 2];
    __shared__ float red[8];
    const int t = threadIdx.x;
    const size_t base = (size_t)blockIdx.x * L;
    const float w0 = w3[0], w1 = w3[1], w2 = w3[2];
    if (t == 0) { xs[0] = 0.f; xs[L + 1] = 0.f; }
    for (int i = t; i < L; i += 256) xs[i + 1] = X[base + i];
    __syncthreads();
    constexpr int E = L / 256;
    float y[E];
    float vmax = -3.4e38f;
#pragma unroll
    for (int i = 0; i < E; ++i) {
        const int c = t + i * 256;
        y[i] = w0 * xs[c] + w1 * xs[c + 1] + w2 * xs[c + 2];
        vmax = fmaxf(vmax, y[i]);
    }
#pragma unroll
    for (int off = 32; off >= 1; off >>= 1) vmax = fmaxf(vmax, __shfl_xor(vmax, off));
    if ((t & 63) == 0) red[t >> 6] = vmax;
    __syncthreads();
    vmax = fmaxf(fmaxf(red[0], red[1]), fmaxf(red[2], red[3]));
    float s = 0.f;
#pragma unroll
    for (int i = 0; i < E; ++i) { y[i] = __expf(y[i] - vmax); s += y[i]; }
#pragma unroll
    for (int off = 32; off >= 1; off >>= 1) s += __shfl_xor(s, off);
    if ((t & 63) == 0) red[4 + (t >> 6)] = s;
    __syncthreads();
    const float inv = 1.f / (red[4] + red[5] + red[6] + red[7]);
#pragma unroll
    for (int i = 0; i < E; ++i) {
        const int c = t + i * 256;
        const float v = y[i] * inv;
        if (OUT_BF16) Yb[base + c] = f2bf(v); else Yf[base + c] = v;
    }
}

extern "C" void kernel_launch(void* const* d_in, const int* in_sizes, int n_in,
                              void* d_out, int out_size, void* d_ws, size_t ws_size,
                              hipStream_t stream)
{
    (void)in_sizes; (void)n_in; (void)out_size; (void)ws_size;
    const float* spec  = (const float*)d_in[0];
    const float* Wih1  = (const float*)d_in[1];
    const float* Whh1  = (const float*)d_in[2];
    const float* bih1  = (const float*)d_in[3];
    const float* bhh1  = (const float*)d_in[4];
    const float* Wih2  = (const float*)d_in[5];
    const float* Whh2  = (const float*)d_in[6];
    const float* bih2  = (const float*)d_in[7];
    const float* bhh2  = (const float*)d_in[8];
    const float* Wih3  = (const float*)d_in[9];
    const float* Whh3  = (const float*)d_in[10];
    const float* bih3  = (const float*)d_in[11];
    const float* bhh3  = (const float*)d_in[12];
    const float* Wih4  = (const float*)d_in[13];
    const float* bih4  = (const float*)d_in[15];
    const float* bhh4  = (const float*)d_in[16];
    const float* w2_1h = (const float*)d_in[17];
    const float* w2_1c = (const float*)d_in[18];
    const float* w3_2h = (const float*)d_in[19];
    const float* w3_2c = (const float*)d_in[20];
    const float* w4_3h = (const float*)d_in[21];
    const float* w4_3c = (const float*)d_in[22];

    char* ws = (char*)d_ws;
    float* g           = (float*)ws;                                  // 64 MiB  [4096*4096 f32]
    float* h           = (float*)(ws + (size_t)67108864);             // 16 MiB
    float* c           = (float*)(ws + (size_t)83886080);             // 16 MiB
    unsigned short* hb = (unsigned short*)(ws + (size_t)100663296);   //  8 MiB (bf16)
    float* cb          = (float*)(ws + (size_t)109051904);            // 16 MiB
    unsigned short* sB = (unsigned short*)(ws + (size_t)125829120);   // 16 MiB (spec bf16)
    unsigned short* wB = (unsigned short*)(ws + (size_t)142606336);   // ~32 MiB (weights bf16)

    // bf16 weight sub-offsets (elements)
    unsigned short* Wih1B = wB;
    unsigned short* Whh1B = wB + (size_t)8388608;
    unsigned short* Wih2B = wB + (size_t)12582912;
    unsigned short* Whh2B = wB + (size_t)14680064;
    unsigned short* Wih3B = wB + (size_t)15728640;
    unsigned short* Whh3B = wB + (size_t)16252928;
    unsigned short* Wih4B = wB + (size_t)16515072;

    // ---- f32 -> bf16 conversions (Whh4 unused: level-4 h_in == 0)
    cvt_f32_bf16<<<2048, 256, 0, stream>>>(spec, sB,    (long)8388608 / 4);
    cvt_f32_bf16<<<2048, 256, 0, stream>>>(Wih1, Wih1B, (long)8388608 / 4);
    cvt_f32_bf16<<<1024, 256, 0, stream>>>(Whh1, Whh1B, (long)4194304 / 4);
    cvt_f32_bf16<<< 512, 256, 0, stream>>>(Wih2, Wih2B, (long)2097152 / 4);
    cvt_f32_bf16<<< 256, 256, 0, stream>>>(Whh2, Whh2B, (long)1048576 / 4);
    cvt_f32_bf16<<< 128, 256, 0, stream>>>(Wih3, Wih3B, (long)524288 / 4);
    cvt_f32_bf16<<<  64, 256, 0, stream>>>(Whh3, Whh3B, (long)262144 / 4);
    cvt_f32_bf16<<<  32, 256, 0, stream>>>(Wih4, Wih4B, (long)131072 / 4);

    // ---- Level 4: M=32768, N=512, K=256 (h=0 -> Whh4 unused)
    gemm_bt<<<dim3(256, 4), 256, 0, stream>>>(sB, Wih4B, 256, nullptr, nullptr, 0, g, 512);
    gate_kernel<false, false><<<2048, 256, 0, stream>>>(g, bih4, bhh4, nullptr, h, c, 7, (long)32768 * 128);
    conv_softmax<256, true ><<<16384, 256, 0, stream>>>(h, w4_3h, nullptr, hb);
    conv_softmax<256, false><<<16384, 256, 0, stream>>>(c, w4_3c, cb, nullptr);

    // ---- Level 3: M=16384, N=1024, K=512+256
    gemm_bt<<<dim3(128, 8), 256, 0, stream>>>(sB, Wih3B, 512, hb, Whh3B, 256, g, 1024);
    gate_kernel<true, false><<<2048, 256, 0, stream>>>(g, bih3, bhh3, cb, h, c, 8, (long)16384 * 256);
    conv_softmax<512, true ><<<8192, 256, 0, stream>>>(h, w3_2h, nullptr, hb);
    conv_softmax<512, false><<<8192, 256, 0, stream>>>(c, w3_2c, cb, nullptr);

    // ---- Level 2: M=8192, N=2048, K=1024+512
    gemm_bt<<<dim3(64, 16), 256, 0, stream>>>(sB, Wih2B, 1024, hb, Whh2B, 512, g, 2048);
    gate_kernel<true, false><<<2048, 256, 0, stream>>>(g, bih2, bhh2, cb, h, c, 9, (long)8192 * 512);
    conv_softmax<1024, true ><<<4096, 256, 0, stream>>>(h, w2_1h, nullptr, hb);
    conv_softmax<1024, false><<<4096, 256, 0, stream>>>(c, w2_1c, cb, nullptr);

    // ---- Level 1: M=4096, N=4096, K=2048+1024; h1 -> d_out (f32)
    gemm_bt<<<dim3(32, 32), 256, 0, stream>>>(sB, Wih1B, 2048, hb, Whh1B, 1024, g, 4096);
    gate_kernel<true, true><<<2048, 256, 0, stream>>>(g, bih1, bhh1, cb, (float*)d_out, nullptr,
                                                      10, (long)4096 * 1024);
}

// Round 3
// 411.276 us; speedup vs baseline: 1.1447x; 1.1447x over previous
//
#include <hip/hip_runtime.h>

// B=4096, ID=2048, OD=1024. 4-level pyramidal LSTM, f32 I/O, bf16 MFMA GEMMs.
// Gate math fused into GEMM epilogue via gate-interleaved weight permutation:
//   converted W row p <- orig row q*H+o, with p = 64*(o>>4) + 16*q + (o&15).
//   A wave's 64-col quadrant then holds gates i,f,g,o (ni=0..3) for 16 outputs,
//   each lane owning one output col -> epilogue needs no cross-lane ops.

typedef __bf16 bf16x8 __attribute__((ext_vector_type(8)));
typedef float f32x4 __attribute__((ext_vector_type(4)));
typedef unsigned short u16x4 __attribute__((ext_vector_type(4)));

__device__ __forceinline__ unsigned short f2bf(float f) {
    union { float f; unsigned int i; } v; v.f = f;
    unsigned int r = v.i + 0x7fffu + ((v.i >> 16) & 1u);
    return (unsigned short)(r >> 16);
}
__device__ __forceinline__ float sigm(float x) { return 1.f / (1.f + __expf(-x)); }
__device__ __forceinline__ float tanh_(float x) { float e = __expf(2.f * x); return 1.f - 2.f / (e + 1.f); }

// ---------------- f32 -> bf16 convert (plain, vectorized)
__global__ __launch_bounds__(256) void cvt_f32_bf16(
    const float* __restrict__ src, unsigned short* __restrict__ dst, long n4)
{
    const long stride = (long)gridDim.x * blockDim.x;
    for (long i = (long)blockIdx.x * blockDim.x + threadIdx.x; i < n4; i += stride) {
        const float4 v = ((const float4*)src)[i];
        u16x4 o;
        o.x = f2bf(v.x); o.y = f2bf(v.y); o.z = f2bf(v.z); o.w = f2bf(v.w);
        ((u16x4*)dst)[i] = o;
    }
}

// ---------------- f32 -> bf16 convert with gate-interleave row permutation
// dst row p (0..4H-1) <- src row r = q*H+o where q=(p>>4)&3, o=((p>>6)<<4)|(p&15)
__global__ __launch_bounds__(256) void cvt_permW(
    const float* __restrict__ src, unsigned short* __restrict__ dst,
    int H, int kshift /*log2(K/4)*/, long n4)
{
    const int kq = 1 << kshift;
    const long stride = (long)gridDim.x * blockDim.x;
    for (long i = (long)blockIdx.x * blockDim.x + threadIdx.x; i < n4; i += stride) {
        const int p = (int)(i >> kshift);
        const int kk = ((int)i & (kq - 1)) << 2;
        const int o = ((p >> 6) << 4) | (p & 15);
        const int q = (p >> 4) & 3;
        const long r = (long)q * H + o;
        const float4 v = *(const float4*)(src + (r << (kshift + 2)) + kk);
        u16x4 w;
        w.x = f2bf(v.x); w.y = f2bf(v.y); w.z = f2bf(v.z); w.w = f2bf(v.w);
        *(u16x4*)(dst + ((long)p << (kshift + 2)) + kk) = w;
    }
}

// ---------------- combined+permuted bias: bsum[p] = bih[r]+bhh[r]
__global__ __launch_bounds__(256) void bias_comb(
    const float* __restrict__ bih, const float* __restrict__ bhh,
    float* __restrict__ bsum, int H, int n)
{
    const int i = blockIdx.x * 256 + threadIdx.x;
    if (i < n) {
        const int o = ((i >> 6) << 4) | (i & 15);
        const int q = (i >> 4) & 3;
        bsum[i] = bih[q * H + o] + bhh[q * H + o];
    }
}

// ---------------- fused GEMM+gates:
// acc[M,4H] = A0@W0^T + A1@W1^T (permuted cols); epilogue computes LSTM cell.
// m97 structure: 128x128 tile, BK=64, 4 waves (2x2 of 64x64), global_load_lds w=16.
template<bool HAS_CIN, bool LAST>
__global__ __launch_bounds__(256) void gemm_fused(
    const unsigned short* __restrict__ A0, const unsigned short* __restrict__ W0, int K0,
    const unsigned short* __restrict__ A1, const unsigned short* __restrict__ W1, int K1,
    const float* __restrict__ bsum, const float* __restrict__ Cin,
    float* __restrict__ Hout, float* __restrict__ Cout, int H)
{
    __shared__ unsigned short As[128 * 64];
    __shared__ unsigned short Bs[128 * 64];
    const int t = threadIdx.x;
    const int w = t >> 6, l = t & 63;
    const int m0 = blockIdx.x * 128, n0 = blockIdx.y * 128;
    const int wr = (w >> 1) * 64, wc = (w & 1) * 64;   // wave's 64x64 quadrant
    const int row8 = l >> 3, colel = (l & 7) * 8;      // staging: lane -> (row-in-8, col*8)
    const int lr = l & 15, lk = (l >> 4) * 8;          // mfma fragment indices

    f32x4 acc[4][4];
#pragma unroll
    for (int i = 0; i < 4; ++i)
#pragma unroll
        for (int j = 0; j < 4; ++j) acc[i][j] = (f32x4){0.f, 0.f, 0.f, 0.f};

    const int nk0 = K0 >> 6, nkt = (K0 + K1) >> 6;
    for (int kt = 0; kt < nkt; ++kt) {
        const unsigned short *Ap, *Wp; int ld, k0;
        if (kt < nk0) { Ap = A0; Wp = W0; ld = K0; k0 = kt << 6; }
        else          { Ap = A1; Wp = W1; ld = K1; k0 = (kt - nk0) << 6; }
#pragma unroll
        for (int r = 0; r < 4; ++r) {
            const int chunk = w * 4 + r;               // 16 chunks of 8 rows x 64 cols
            const unsigned short* ga = Ap + (size_t)(m0 + chunk * 8 + row8) * ld + (k0 + colel);
            const unsigned short* gb = Wp + (size_t)(n0 + chunk * 8 + row8) * ld + (k0 + colel);
            __builtin_amdgcn_global_load_lds((const __attribute__((address_space(1))) void*)ga,
                (__attribute__((address_space(3))) void*)(&As[chunk * 512]), 16, 0, 0);
            __builtin_amdgcn_global_load_lds((const __attribute__((address_space(1))) void*)gb,
                (__attribute__((address_space(3))) void*)(&Bs[chunk * 512]), 16, 0, 0);
        }
        __syncthreads();
#pragma unroll
        for (int ks = 0; ks < 2; ++ks) {
            bf16x8 af[4], bfr[4];
#pragma unroll
            for (int mi = 0; mi < 4; ++mi)
                af[mi] = *(const bf16x8*)&As[(wr + mi * 16 + lr) * 64 + ks * 32 + lk];
#pragma unroll
            for (int ni = 0; ni < 4; ++ni)
                bfr[ni] = *(const bf16x8*)&Bs[(wc + ni * 16 + lr) * 64 + ks * 32 + lk];
#pragma unroll
            for (int mi = 0; mi < 4; ++mi)
#pragma unroll
                for (int ni = 0; ni < 4; ++ni)
                    acc[mi][ni] = __builtin_amdgcn_mfma_f32_16x16x32_bf16(
                        af[mi], bfr[ni], acc[mi][ni], 0, 0, 0);
        }
        __syncthreads();
    }
    // ---- fused LSTM-cell epilogue
    // col block n0+wc covers outputs o_base..o_base+15 (all 4 gates); lane owns one o.
    const int o = (((n0 + wc) >> 6) << 4) + (l & 15);
    const float b0 = bsum[n0 + wc +      (l & 15)];
    const float b1 = bsum[n0 + wc + 16 + (l & 15)];
    const float b2 = bsum[n0 + wc + 32 + (l & 15)];
    const float b3 = bsum[n0 + wc + 48 + (l & 15)];
#pragma unroll
    for (int mi = 0; mi < 4; ++mi)
#pragma unroll
        for (int j = 0; j < 4; ++j) {
            const int m = m0 + wr + mi * 16 + (l >> 4) * 4 + j;
            const float gi = acc[mi][0][j] + b0;
            const float gf = acc[mi][1][j] + b1;
            const float gg = acc[mi][2][j] + b2;
            const float go = acc[mi][3][j] + b3;
            float c2 = sigm(gi) * tanh_(gg);
            if (HAS_CIN) c2 += sigm(gf) * Cin[(size_t)m * H + o];
            const float h2 = sigm(go) * tanh_(c2);
            Hout[(size_t)m * H + o] = h2;
            if (!LAST) Cout[(size_t)m * H + o] = c2;
        }
}

// ---------------- conv1d(k=3,pad=1) + row softmax; one block per row of length L
template<int L, bool OUT_BF16>
__global__ __launch_bounds__(256) void conv_softmax(
    const float* __restrict__ X, const float* __restrict__ w3,
    float* __restrict__ Yf, unsigned short* __restrict__ Yb)
{
    __shared__ float xs[L + 2];
    __shared__ float red[8];
    const int t = threadIdx.x;
    const size_t base = (size_t)blockIdx.x * L;
    const float w0 = w3[0], w1 = w3[1], w2 = w3[2];
    if (t == 0) { xs[0] = 0.f; xs[L + 1] = 0.f; }
    for (int i = t; i < L; i += 256) xs[i + 1] = X[base + i];
    __syncthreads();
    constexpr int E = L / 256;
    float y[E];
    float vmax = -3.4e38f;
#pragma unroll
    for (int i = 0; i < E; ++i) {
        const int c = t + i * 256;
        y[i] = w0 * xs[c] + w1 * xs[c + 1] + w2 * xs[c + 2];
        vmax = fmaxf(vmax, y[i]);
    }
#pragma unroll
    for (int off = 32; off >= 1; off >>= 1) vmax = fmaxf(vmax, __shfl_xor(vmax, off));
    if ((t & 63) == 0) red[t >> 6] = vmax;
    __syncthreads();
    vmax = fmaxf(fmaxf(red[0], red[1]), fmaxf(red[2], red[3]));
    float s = 0.f;
#pragma unroll
    for (int i = 0; i < E; ++i) { y[i] = __expf(y[i] - vmax); s += y[i]; }
#pragma unroll
    for (int off = 32; off >= 1; off >>= 1) s += __shfl_xor(s, off);
    if ((t & 63) == 0) red[4 + (t >> 6)] = s;
    __syncthreads();
    const float inv = 1.f / (red[4] + red[5] + red[6] + red[7]);
#pragma unroll
    for (int i = 0; i < E; ++i) {
        const int c = t + i * 256;
        const float v = y[i] * inv;
        if (OUT_BF16) Yb[base + c] = f2bf(v); else Yf[base + c] = v;
    }
}

extern "C" void kernel_launch(void* const* d_in, const int* in_sizes, int n_in,
                              void* d_out, int out_size, void* d_ws, size_t ws_size,
                              hipStream_t stream)
{
    (void)in_sizes; (void)n_in; (void)out_size; (void)ws_size;
    const float* spec  = (const float*)d_in[0];
    const float* Wih1  = (const float*)d_in[1];
    const float* Whh1  = (const float*)d_in[2];
    const float* bih1  = (const float*)d_in[3];
    const float* bhh1  = (const float*)d_in[4];
    const float* Wih2  = (const float*)d_in[5];
    const float* Whh2  = (const float*)d_in[6];
    const float* bih2  = (const float*)d_in[7];
    const float* bhh2  = (const float*)d_in[8];
    const float* Wih3  = (const float*)d_in[9];
    const float* Whh3  = (const float*)d_in[10];
    const float* bih3  = (const float*)d_in[11];
    const float* bhh3  = (const float*)d_in[12];
    const float* Wih4  = (const float*)d_in[13];
    const float* bih4  = (const float*)d_in[15];
    const float* bhh4  = (const float*)d_in[16];
    const float* w2_1h = (const float*)d_in[17];
    const float* w2_1c = (const float*)d_in[18];
    const float* w3_2h = (const float*)d_in[19];
    const float* w3_2c = (const float*)d_in[20];
    const float* w4_3h = (const float*)d_in[21];
    const float* w4_3c = (const float*)d_in[22];

    char* ws = (char*)d_ws;
    float* h           = (float*)ws;                                  // 16 MiB [4096*1024 f32 max]
    float* c           = (float*)(ws + (size_t)16777216);             // 16 MiB
    float* cb          = (float*)(ws + (size_t)33554432);             // 16 MiB
    unsigned short* hb = (unsigned short*)(ws + (size_t)50331648);    //  8 MiB (bf16)
    unsigned short* sB = (unsigned short*)(ws + (size_t)58720256);    // 16 MiB (spec bf16)
    unsigned short* wB = (unsigned short*)(ws + (size_t)75497472);    // ~32 MiB (perm bf16 weights)
    float* bs1         = (float*)(ws + (size_t)109051904);            // 16 KiB each
    float* bs2         = bs1 + 4096;
    float* bs3         = bs2 + 4096;
    float* bs4         = bs3 + 4096;

    // permuted bf16 weight sub-offsets (elements)
    unsigned short* Wih1B = wB;                          // 4096x2048
    unsigned short* Whh1B = wB + (size_t)8388608;        // 4096x1024
    unsigned short* Wih2B = wB + (size_t)12582912;       // 2048x1024
    unsigned short* Whh2B = wB + (size_t)14680064;       // 2048x512
    unsigned short* Wih3B = wB + (size_t)15728640;       // 1024x512
    unsigned short* Whh3B = wB + (size_t)16252928;       // 1024x256
    unsigned short* Wih4B = wB + (size_t)16515072;       // 512x256

    // ---- conversions (Whh4 unused: level-4 h_in == 0)
    cvt_f32_bf16<<<2048, 256, 0, stream>>>(spec, sB, (long)8388608 / 4);
    cvt_permW<<<2048, 256, 0, stream>>>(Wih1, Wih1B, 1024, 9, (long)8388608 / 4);
    cvt_permW<<<1024, 256, 0, stream>>>(Whh1, Whh1B, 1024, 8, (long)4194304 / 4);
    cvt_permW<<< 512, 256, 0, stream>>>(Wih2, Wih2B,  512, 8, (long)2097152 / 4);
    cvt_permW<<< 256, 256, 0, stream>>>(Whh2, Whh2B,  512, 7, (long)1048576 / 4);
    cvt_permW<<< 128, 256, 0, stream>>>(Wih3, Wih3B,  256, 7, (long)524288 / 4);
    cvt_permW<<<  64, 256, 0, stream>>>(Whh3, Whh3B,  256, 6, (long)262144 / 4);
    cvt_permW<<<  32, 256, 0, stream>>>(Wih4, Wih4B,  128, 6, (long)131072 / 4);
    bias_comb<<<16, 256, 0, stream>>>(bih1, bhh1, bs1, 1024, 4096);
    bias_comb<<< 8, 256, 0, stream>>>(bih2, bhh2, bs2,  512, 2048);
    bias_comb<<< 4, 256, 0, stream>>>(bih3, bhh3, bs3,  256, 1024);
    bias_comb<<< 2, 256, 0, stream>>>(bih4, bhh4, bs4,  128,  512);

    // ---- Level 4: M=32768, N=512 (H=128), K=256; no c_in
    gemm_fused<false, false><<<dim3(256, 4), 256, 0, stream>>>(
        sB, Wih4B, 256, nullptr, nullptr, 0, bs4, nullptr, h, c, 128);
    conv_softmax<256, true ><<<16384, 256, 0, stream>>>(h, w4_3h, nullptr, hb);
    conv_softmax<256, false><<<16384, 256, 0, stream>>>(c, w4_3c, cb, nullptr);

    // ---- Level 3: M=16384, N=1024 (H=256), K=512+256
    gemm_fused<true, false><<<dim3(128, 8), 256, 0, stream>>>(
        sB, Wih3B, 512, hb, Whh3B, 256, bs3, cb, h, c, 256);
    conv_softmax<512, true ><<<8192, 256, 0, stream>>>(h, w3_2h, nullptr, hb);
    conv_softmax<512, false><<<8192, 256, 0, stream>>>(c, w3_2c, cb, nullptr);

    // ---- Level 2: M=8192, N=2048 (H=512), K=1024+512
    gemm_fused<true, false><<<dim3(64, 16), 256, 0, stream>>>(
        sB, Wih2B, 1024, hb, Whh2B, 512, bs2, cb, h, c, 512);
    conv_softmax<1024, true ><<<4096, 256, 0, stream>>>(h, w2_1h, nullptr, hb);
    conv_softmax<1024, false><<<4096, 256, 0, stream>>>(c, w2_1c, cb, nullptr);

    // ---- Level 1: M=4096, N=4096 (H=1024), K=2048+1024; h1 -> d_out (f32)
    gemm_fused<true, true><<<dim3(32, 32), 256, 0, stream>>>(
        sB, Wih1B, 2048, hb, Whh1B, 1024, bs1, cb, (float*)d_out, nullptr, 1024);
}

// Round 4
// 354.563 us; speedup vs baseline: 1.3278x; 1.1600x over previous
//
#include <hip/hip_runtime.h>

// B=4096, ID=2048, OD=1024. 4-level pyramidal LSTM, f32 I/O.
// GEMM: 256x256-tile 8-phase pipeline (T2 swizzle + T3/T4 counted vmcnt + T5 setprio),
// LSTM gate math fused in epilogue via gate-interleaved weight permutation
// (W row p <- orig row q*H+o, p = 64*(o>>4) + 16*q + (o&15)).

typedef __bf16 bf16x8 __attribute__((ext_vector_type(8)));
typedef float f32x4 __attribute__((ext_vector_type(4)));
typedef unsigned short u16x4 __attribute__((ext_vector_type(4)));

#define AS1 __attribute__((address_space(1)))
#define AS3 __attribute__((address_space(3)))

__device__ __forceinline__ unsigned short f2bf(float f) {
    union { float f; unsigned int i; } v; v.f = f;
    unsigned int r = v.i + 0x7fffu + ((v.i >> 16) & 1u);
    return (unsigned short)(r >> 16);
}
__device__ __forceinline__ float sigm(float x) { return 1.f / (1.f + __expf(-x)); }
__device__ __forceinline__ float tanh_(float x) { float e = __expf(2.f * x); return 1.f - 2.f / (e + 1.f); }

// ---------------- f32 -> bf16 (flat)
__global__ __launch_bounds__(256) void cvt_f32_bf16(
    const float* __restrict__ src, unsigned short* __restrict__ dst, long n4)
{
    const long stride = (long)gridDim.x * blockDim.x;
    for (long i = (long)blockIdx.x * blockDim.x + threadIdx.x; i < n4; i += stride) {
        const float4 v = ((const float4*)src)[i];
        u16x4 o; o.x = f2bf(v.x); o.y = f2bf(v.y); o.z = f2bf(v.z); o.w = f2bf(v.w);
        ((u16x4*)dst)[i] = o;
    }
}

// ---------------- f32 spec -> bf16 rows of an A_cat panel (contiguous src, strided dst)
__global__ __launch_bounds__(256) void cvt_specA(
    const float* __restrict__ spec, unsigned short* __restrict__ dst,
    int ks2 /*log2(K0/4)*/, int dstld, long n4)
{
    const long stride = (long)gridDim.x * blockDim.x;
    for (long i = (long)blockIdx.x * blockDim.x + threadIdx.x; i < n4; i += stride) {
        const float4 v = ((const float4*)spec)[i];
        const long m = i >> ks2;
        const int col = ((int)(i & ((1L << ks2) - 1))) << 2;
        u16x4 o; o.x = f2bf(v.x); o.y = f2bf(v.y); o.z = f2bf(v.z); o.w = f2bf(v.w);
        *(u16x4*)(dst + m * dstld + col) = o;
    }
}

// ---------------- f32 -> bf16 weight convert, gate-interleave rows, concat cols
__global__ __launch_bounds__(256) void cvt_permW(
    const float* __restrict__ src, unsigned short* __restrict__ dst,
    int H, int kshift /*log2(Ksrc/4)*/, int dstld, int dstcol, long n4)
{
    const int kq = 1 << kshift;
    const long stride = (long)gridDim.x * blockDim.x;
    for (long i = (long)blockIdx.x * blockDim.x + threadIdx.x; i < n4; i += stride) {
        const int p = (int)(i >> kshift);
        const int kk = ((int)i & (kq - 1)) << 2;
        const int o = ((p >> 6) << 4) | (p & 15);
        const int q = (p >> 4) & 3;
        const long r = (long)q * H + o;
        const float4 v = *(const float4*)(src + (r << (kshift + 2)) + kk);
        u16x4 w; w.x = f2bf(v.x); w.y = f2bf(v.y); w.z = f2bf(v.z); w.w = f2bf(v.w);
        *(u16x4*)(dst + (long)p * dstld + dstcol + kk) = w;
    }
}

// ---------------- combined+permuted bias
__global__ __launch_bounds__(256) void bias_comb(
    const float* __restrict__ bih, const float* __restrict__ bhh,
    float* __restrict__ bsum, int H, int n)
{
    const int i = blockIdx.x * 256 + threadIdx.x;
    if (i < n) {
        const int o = ((i >> 6) << 4) | (i & 15);
        const int q = (i >> 4) & 3;
        bsum[i] = bih[q * H + o] + bhh[q * H + o];
    }
}

// ---------------- 256x256 8-phase fused GEMM+LSTM-cell
// A[M,K], W[N=4H,K] bf16 (W gate-permuted). 8 waves (2M x 4N), per-wave 128x64.
// LDS 128KB: [q][A/B][half] 16KB regions, linear write via global_load_lds,
// XOR-swizzled source cols + XOR-swizzled ds_read (involution, T2).
#define QUAD(S, NS, BF)                                                                     \
    { _Pragma("unroll") for (int mi = 0; mi < 4; ++mi) {                                    \
        _Pragma("unroll") for (int ni = 0; ni < 2; ++ni) {                                  \
            acc[(S)*4+mi][(NS)*2+ni] = __builtin_amdgcn_mfma_f32_16x16x32_bf16(             \
                aF[mi][0], BF[ni][0], acc[(S)*4+mi][(NS)*2+ni], 0, 0, 0);                   \
            acc[(S)*4+mi][(NS)*2+ni] = __builtin_amdgcn_mfma_f32_16x16x32_bf16(             \
                aF[mi][1], BF[ni][1], acc[(S)*4+mi][(NS)*2+ni], 0, 0, 0);                   \
    } } }

#define GLL(gsrc, loff) __builtin_amdgcn_global_load_lds(                                   \
    (const AS1 void*)(gsrc), (AS3 void*)(lds + (loff)), 16, 0, 0)

#define BAR_LGKM                                                                            \
    __builtin_amdgcn_s_barrier();                                                           \
    asm volatile("s_waitcnt lgkmcnt(0)" ::: "memory");                                      \
    __builtin_amdgcn_sched_barrier(0);

#define PH_END                                                                              \
    __builtin_amdgcn_s_setprio(0);                                                          \
    __builtin_amdgcn_s_barrier();                                                           \
    __builtin_amdgcn_sched_barrier(0);

template<bool HAS_CIN, bool LAST>
__global__ __launch_bounds__(512, 2) void gemm8(
    const unsigned short* __restrict__ A, const unsigned short* __restrict__ W, const int K,
    const float* __restrict__ bsum, const float* __restrict__ Cin,
    float* __restrict__ Hout, float* __restrict__ Cout, const int H)
{
    __shared__ __align__(16) char lds[131072];
    const int t = threadIdx.x;
    const int w = t >> 6, l = t & 63;
    const int wr = w >> 2, wc = w & 3;                 // 2 x 4 wave grid
    const int m0 = blockIdx.x * 256, n0 = blockIdx.y * 256;

    // staging: thread covers rows w*16+{0,8}+(l>>3), swizzled col granule (l&7)^(l>>3)
    const int colsw = ((l & 7) ^ (l >> 3)) * 8;        // elements
    const size_t k128 = (size_t)128 * K;
    const size_t aoff0 = (size_t)(m0 + w * 16 + (l >> 3)) * K + colsw;
    const size_t aoff1 = aoff0 + (size_t)8 * K;
    const size_t boff0 = (size_t)(n0 + w * 16 + (l >> 3)) * K + colsw;
    const size_t boff1 = boff0 + (size_t)8 * K;
    const int sd0 = w * 2048 + l * 16;                 // LDS byte dest (within region)
    const int sd1 = sd0 + 1024;

    // ds_read: row = sub*... + (l&15), swizzled granule (ks*4+(l>>4)) ^ (l&7)
    const int lr128 = (l & 15) * 128;
    const int sw0 = (((l >> 4)    ) ^ (l & 7)) * 16;
    const int sw1 = (((l >> 4) + 4) ^ (l & 7)) * 16;

    f32x4 acc[8][4];
#pragma unroll
    for (int i = 0; i < 8; ++i)
#pragma unroll
        for (int j = 0; j < 4; ++j) acc[i][j] = (f32x4){0.f, 0.f, 0.f, 0.f};

    const int NT = K >> 6;  // >= 4 for all levels

    // ---- prologue: tile0 all 4 halves, tile1 {Bh0,Bh1,Ah0} (newest 3)
    GLL(A + aoff0, sd0);                     GLL(A + aoff1, sd1);                 // A t0 h0 @0
    GLL(A + aoff0 + k128, 16384 + sd0);      GLL(A + aoff1 + k128, 16384 + sd1);  // A t0 h1
    GLL(W + boff0, 32768 + sd0);             GLL(W + boff1, 32768 + sd1);         // B t0 h0
    GLL(W + boff0 + k128, 49152 + sd0);      GLL(W + boff1 + k128, 49152 + sd1);  // B t0 h1
    GLL(W + boff0 + 64, 98304 + sd0);        GLL(W + boff1 + 64, 98304 + sd1);    // B t1 h0
    GLL(W + boff0 + k128 + 64, 114688 + sd0);GLL(W + boff1 + k128 + 64, 114688 + sd1); // B t1 h1
    GLL(A + aoff0 + 64, 65536 + sd0);        GLL(A + aoff1 + 64, 65536 + sd1);    // A t1 h0
    asm volatile("s_waitcnt vmcnt(6)" ::: "memory");
    __builtin_amdgcn_s_barrier();
    __builtin_amdgcn_sched_barrier(0);

    bf16x8 aF[4][2], bF0[2][2], bF1[2][2];

    for (int tt = 0; tt < NT; ++tt) {
        const int q = tt & 1, qn = q ^ 1;
        const int rbA = (q << 16) + (wr << 14) + lr128;
        const int rbB = (q << 16) + 32768 + wc * 8192 + lr128;

        // ---- P1: ds_read A-lo(8) + B-lo(4); stage A-h1(tt+1); MFMA Q(0,0)
#pragma unroll
        for (int mi = 0; mi < 4; ++mi) {
            aF[mi][0] = *(const bf16x8*)(lds + rbA + mi * 2048 + sw0);
            aF[mi][1] = *(const bf16x8*)(lds + rbA + mi * 2048 + sw1);
        }
#pragma unroll
        for (int ni = 0; ni < 2; ++ni) {
            bF0[ni][0] = *(const bf16x8*)(lds + rbB + ni * 2048 + sw0);
            bF0[ni][1] = *(const bf16x8*)(lds + rbB + ni * 2048 + sw1);
        }
        if (tt + 1 < NT) {
            const size_t ko = (size_t)(tt + 1) * 64;
            GLL(A + aoff0 + k128 + ko, (qn << 16) + 16384 + sd0);
            GLL(A + aoff1 + k128 + ko, (qn << 16) + 16384 + sd1);
        }
        BAR_LGKM;
        __builtin_amdgcn_s_setprio(1);
        QUAD(0, 0, bF0);
        PH_END;

        // ---- P2: ds_read B-hi(4); MFMA Q(0,1)
#pragma unroll
        for (int ni = 0; ni < 2; ++ni) {
            bF1[ni][0] = *(const bf16x8*)(lds + rbB + 4096 + ni * 2048 + sw0);
            bF1[ni][1] = *(const bf16x8*)(lds + rbB + 4096 + ni * 2048 + sw1);
        }
        BAR_LGKM;
        __builtin_amdgcn_s_setprio(1);
        QUAD(0, 1, bF1);
        PH_END;

        // ---- P3: ds_read A-hi(8); stage B-h0(tt+2); MFMA Q(1,1)
#pragma unroll
        for (int mi = 0; mi < 4; ++mi) {
            aF[mi][0] = *(const bf16x8*)(lds + rbA + 8192 + mi * 2048 + sw0);
            aF[mi][1] = *(const bf16x8*)(lds + rbA + 8192 + mi * 2048 + sw1);
        }
        if (tt + 2 < NT) {
            const size_t ko = (size_t)(tt + 2) * 64;
            GLL(W + boff0 + ko, (q << 16) + 32768 + sd0);
            GLL(W + boff1 + ko, (q << 16) + 32768 + sd1);
        }
        BAR_LGKM;
        __builtin_amdgcn_s_setprio(1);
        QUAD(1, 1, bF1);
        PH_END;

        // ---- P4: stage B-h1(tt+2) + A-h0(tt+2); counted vmcnt; MFMA Q(1,0)
        if (tt + 2 < NT) {
            const size_t ko = (size_t)(tt + 2) * 64;
            GLL(W + boff0 + k128 + ko, (q << 16) + 49152 + sd0);
            GLL(W + boff1 + k128 + ko, (q << 16) + 49152 + sd1);
            GLL(A + aoff0 + ko, (q << 16) + sd0);
            GLL(A + aoff1 + ko, (q << 16) + sd1);
        }
        if (tt < NT - 2) { asm volatile("s_waitcnt vmcnt(6)" ::: "memory"); }
        else             { asm volatile("s_waitcnt vmcnt(0)" ::: "memory"); }
        __builtin_amdgcn_s_barrier();
        __builtin_amdgcn_sched_barrier(0);
        __builtin_amdgcn_s_setprio(1);
        QUAD(1, 0, bF0);
        PH_END;
    }

    // ---- fused LSTM-cell epilogue: wave's 64-col group = 4 gates x 16 outputs
    const int ocol = (n0 >> 6) * 16 + wc * 16 + (l & 15);
    const int bb = n0 + wc * 64 + (l & 15);
    const float b0 = bsum[bb], b1 = bsum[bb + 16], b2 = bsum[bb + 32], b3 = bsum[bb + 48];
    const int mrow0 = m0 + wr * 128 + (l >> 4) * 4;
#pragma unroll
    for (int mi = 0; mi < 8; ++mi)
#pragma unroll
        for (int j = 0; j < 4; ++j) {
            const size_t m = (size_t)(mrow0 + mi * 16 + j);
            const float gi = acc[mi][0][j] + b0;
            const float gf = acc[mi][1][j] + b1;
            const float gg = acc[mi][2][j] + b2;
            const float go = acc[mi][3][j] + b3;
            float c2 = sigm(gi) * tanh_(gg);
            if (HAS_CIN) c2 += sigm(gf) * Cin[m * H + ocol];
            const float h2 = sigm(go) * tanh_(c2);
            Hout[m * H + ocol] = h2;
            if (!LAST) Cout[m * H + ocol] = c2;
        }
}

// ---------------- conv1d(k=3,pad=1) + row softmax; one block per row
template<int L, bool OUT_BF16>
__global__ __launch_bounds__(256) void conv_softmax(
    const float* __restrict__ X, const float* __restrict__ w3,
    float* __restrict__ Yf, unsigned short* __restrict__ Yb, int ldYb)
{
    __shared__ float xs[L + 2];
    __shared__ float red[8];
    const int t = threadIdx.x;
    const size_t base = (size_t)blockIdx.x * L;
    const float w0 = w3[0], w1 = w3[1], w2 = w3[2];
    if (t == 0) { xs[0] = 0.f; xs[L + 1] = 0.f; }
    for (int i = t; i < L; i += 256) xs[i + 1] = X[base + i];
    __syncthreads();
    constexpr int E = L / 256;
    float y[E];
    float vmax = -3.4e38f;
#pragma unroll
    for (int i = 0; i < E; ++i) {
        const int c = t + i * 256;
        y[i] = w0 * xs[c] + w1 * xs[c + 1] + w2 * xs[c + 2];
        vmax = fmaxf(vmax, y[i]);
    }
#pragma unroll
    for (int off = 32; off >= 1; off >>= 1) vmax = fmaxf(vmax, __shfl_xor(vmax, off));
    if ((t & 63) == 0) red[t >> 6] = vmax;
    __syncthreads();
    vmax = fmaxf(fmaxf(red[0], red[1]), fmaxf(red[2], red[3]));
    float s = 0.f;
#pragma unroll
    for (int i = 0; i < E; ++i) { y[i] = __expf(y[i] - vmax); s += y[i]; }
#pragma unroll
    for (int off = 32; off >= 1; off >>= 1) s += __shfl_xor(s, off);
    if ((t & 63) == 0) red[4 + (t >> 6)] = s;
    __syncthreads();
    const float inv = 1.f / (red[4] + red[5] + red[6] + red[7]);
#pragma unroll
    for (int i = 0; i < E; ++i) {
        const int c = t + i * 256;
        const float v = y[i] * inv;
        if (OUT_BF16) Yb[(size_t)blockIdx.x * ldYb + c] = f2bf(v);
        else          Yf[base + c] = v;
    }
}

extern "C" void kernel_launch(void* const* d_in, const int* in_sizes, int n_in,
                              void* d_out, int out_size, void* d_ws, size_t ws_size,
                              hipStream_t stream)
{
    (void)in_sizes; (void)n_in; (void)out_size; (void)ws_size;
    const float* spec  = (const float*)d_in[0];
    const float* Wih1  = (const float*)d_in[1];
    const float* Whh1  = (const float*)d_in[2];
    const float* bih1  = (const float*)d_in[3];
    const float* bhh1  = (const float*)d_in[4];
    const float* Wih2  = (const float*)d_in[5];
    const float* Whh2  = (const float*)d_in[6];
    const float* bih2  = (const float*)d_in[7];
    const float* bhh2  = (const float*)d_in[8];
    const float* Wih3  = (const float*)d_in[9];
    const float* Whh3  = (const float*)d_in[10];
    const float* bih3  = (const float*)d_in[11];
    const float* bhh3  = (const float*)d_in[12];
    const float* Wih4  = (const float*)d_in[13];
    const float* bih4  = (const float*)d_in[15];
    const float* bhh4  = (const float*)d_in[16];
    const float* w2_1h = (const float*)d_in[17];
    const float* w2_1c = (const float*)d_in[18];
    const float* w3_2h = (const float*)d_in[19];
    const float* w3_2c = (const float*)d_in[20];
    const float* w4_3h = (const float*)d_in[21];
    const float* w4_3c = (const float*)d_in[22];

    char* ws = (char*)d_ws;
    float*          h   = (float*)(ws + 0);                         // 16 MiB
    float*          c   = (float*)(ws + (size_t)16777216);          // 16 MiB
    float*          cb  = (float*)(ws + (size_t)33554432);          // 16 MiB
    unsigned short* sB  = (unsigned short*)(ws + (size_t)50331648); // 16 MiB (spec bf16, L4 A)
    unsigned short* X   = (unsigned short*)(ws + (size_t)67108864); // 24 MiB (A_cat3 -> A_cat1)
    unsigned short* Y   = (unsigned short*)(ws + (size_t)92274688); // 24 MiB (A_cat2)
    unsigned short* Wc1 = (unsigned short*)(ws + (size_t)117440512);// 24 MiB
    unsigned short* Wc2 = (unsigned short*)(ws + (size_t)142606336);//  6 MiB
    unsigned short* Wc3 = (unsigned short*)(ws + (size_t)148897792);// 1.5 MiB
    unsigned short* W4  = (unsigned short*)(ws + (size_t)150470656);// 0.25 MiB
    float*          bs1 = (float*)(ws + (size_t)150732800);
    float*          bs2 = bs1 + 4096;
    float*          bs3 = bs2 + 4096;
    float*          bs4 = bs3 + 4096;

    // ---- conversions (Whh4 unused: level-4 h_in == 0)
    cvt_f32_bf16<<<2048, 256, 0, stream>>>(spec, sB, 2097152);
    cvt_specA<<<2048, 256, 0, stream>>>(spec, X, 7,  768, 2097152);   // A_cat3 spec part
    cvt_specA<<<2048, 256, 0, stream>>>(spec, Y, 8, 1536, 2097152);   // A_cat2 spec part
    cvt_permW<<<2048, 256, 0, stream>>>(Wih1, Wc1, 1024, 9, 3072,    0, 2097152);
    cvt_permW<<<1024, 256, 0, stream>>>(Whh1, Wc1, 1024, 8, 3072, 2048, 1048576);
    cvt_permW<<< 512, 256, 0, stream>>>(Wih2, Wc2,  512, 8, 1536,    0,  524288);
    cvt_permW<<< 256, 256, 0, stream>>>(Whh2, Wc2,  512, 7, 1536, 1024,  262144);
    cvt_permW<<< 128, 256, 0, stream>>>(Wih3, Wc3,  256, 7,  768,    0,  131072);
    cvt_permW<<<  64, 256, 0, stream>>>(Whh3, Wc3,  256, 6,  768,  512,   65536);
    cvt_permW<<<  32, 256, 0, stream>>>(Wih4, W4,   128, 6,  256,    0,   32768);
    bias_comb<<<16, 256, 0, stream>>>(bih1, bhh1, bs1, 1024, 4096);
    bias_comb<<< 8, 256, 0, stream>>>(bih2, bhh2, bs2,  512, 2048);
    bias_comb<<< 4, 256, 0, stream>>>(bih3, bhh3, bs3,  256, 1024);
    bias_comb<<< 2, 256, 0, stream>>>(bih4, bhh4, bs4,  128,  512);

    // ---- Level 4: M=32768, N=512 (H=128), K=256
    gemm8<false, false><<<dim3(128, 2), 512, 0, stream>>>(sB, W4, 256, bs4, nullptr, h, c, 128);
    conv_softmax<256, true ><<<16384, 256, 0, stream>>>(h, w4_3h, nullptr, X + 512, 768);
    conv_softmax<256, false><<<16384, 256, 0, stream>>>(c, w4_3c, cb, nullptr, 0);

    // ---- Level 3: M=16384, N=1024 (H=256), K=768
    gemm8<true, false><<<dim3(64, 4), 512, 0, stream>>>(X, Wc3, 768, bs3, cb, h, c, 256);
    cvt_specA<<<2048, 256, 0, stream>>>(spec, X, 9, 3072, 2097152);   // A_cat1 spec part (X free)
    conv_softmax<512, true ><<<8192, 256, 0, stream>>>(h, w3_2h, nullptr, Y + 1024, 1536);
    conv_softmax<512, false><<<8192, 256, 0, stream>>>(c, w3_2c, cb, nullptr, 0);

    // ---- Level 2: M=8192, N=2048 (H=512), K=1536
    gemm8<true, false><<<dim3(32, 8), 512, 0, stream>>>(Y, Wc2, 1536, bs2, cb, h, c, 512);
    conv_softmax<1024, true ><<<4096, 256, 0, stream>>>(h, w2_1h, nullptr, X + 2048, 3072);
    conv_softmax<1024, false><<<4096, 256, 0, stream>>>(c, w2_1c, cb, nullptr, 0);

    // ---- Level 1: M=4096, N=4096 (H=1024), K=3072; h1 -> d_out (f32)
    gemm8<true, true><<<dim3(16, 16), 512, 0, stream>>>(X, Wc1, 3072, bs1, cb, (float*)d_out, nullptr, 1024);
}

// Round 5
// 317.311 us; speedup vs baseline: 1.4837x; 1.1174x over previous
//
#include <hip/hip_runtime.h>

// B=4096, ID=2048, OD=1024. 4-level pyramidal LSTM, f32 I/O.
// GEMM: 256x256 8-phase pipeline; compiler-scheduled fine-grained lgkmcnt
// (no hard drains), counted vmcnt(6) once per K-tile, T2 LDS swizzle,
// T5 setprio, T1 XCD block swizzle. LSTM cell fused in epilogue via
// gate-interleaved weight permutation (W row p <- q*H+o, p=64*(o>>4)+16*q+(o&15)).

typedef __bf16 bf16x8 __attribute__((ext_vector_type(8)));
typedef float f32x4 __attribute__((ext_vector_type(4)));
typedef unsigned short u16x4 __attribute__((ext_vector_type(4)));

#define AS1 __attribute__((address_space(1)))
#define AS3 __attribute__((address_space(3)))

__device__ __forceinline__ unsigned short f2bf(float f) {
    union { float f; unsigned int i; } v; v.f = f;
    unsigned int r = v.i + 0x7fffu + ((v.i >> 16) & 1u);
    return (unsigned short)(r >> 16);
}
__device__ __forceinline__ float sigm(float x) { return 1.f / (1.f + __expf(-x)); }
__device__ __forceinline__ float tanh_(float x) { float e = __expf(2.f * x); return 1.f - 2.f / (e + 1.f); }

// ---------------- spec f32 -> bf16, three destinations (flat, A_cat3, A_cat2)
__global__ __launch_bounds__(256) void cvt_spec3(
    const float* __restrict__ spec, unsigned short* __restrict__ sB,
    unsigned short* __restrict__ X, unsigned short* __restrict__ Y, long n4)
{
    const long stride = (long)gridDim.x * blockDim.x;
    for (long i = (long)blockIdx.x * blockDim.x + threadIdx.x; i < n4; i += stride) {
        const float4 v = ((const float4*)spec)[i];
        u16x4 o; o.x = f2bf(v.x); o.y = f2bf(v.y); o.z = f2bf(v.z); o.w = f2bf(v.w);
        ((u16x4*)sB)[i] = o;
        const long b = i >> 9;            // 512 granules per 2048-el row
        const int c4 = (int)(i & 511);
        *(u16x4*)(X + (b * 4 + (c4 >> 7)) * 768  + ((c4 & 127) << 2)) = o;
        *(u16x4*)(Y + (b * 2 + (c4 >> 8)) * 1536 + ((c4 & 255) << 2)) = o;
    }
}

// ---------------- spec f32 -> bf16 rows of A_cat1 (ld 3072)
__global__ __launch_bounds__(256) void cvt_specA(
    const float* __restrict__ spec, unsigned short* __restrict__ dst, long n4)
{
    const long stride = (long)gridDim.x * blockDim.x;
    for (long i = (long)blockIdx.x * blockDim.x + threadIdx.x; i < n4; i += stride) {
        const float4 v = ((const float4*)spec)[i];
        const long m = i >> 9;
        const int col = ((int)(i & 511)) << 2;
        u16x4 o; o.x = f2bf(v.x); o.y = f2bf(v.y); o.z = f2bf(v.z); o.w = f2bf(v.w);
        *(u16x4*)(dst + m * 3072 + col) = o;
    }
}

// ---------------- merged weight convert+permute (7 segments)
struct PSeg { const float* src; unsigned short* dst; long g0; int H; int kshift; int dstld; int dstcol; };
struct PArgs { PSeg s[7]; long total; };

__global__ __launch_bounds__(256) void cvt_permW_all(PArgs pa)
{
    const long stride = (long)gridDim.x * blockDim.x;
    for (long gi = (long)blockIdx.x * blockDim.x + threadIdx.x; gi < pa.total; gi += stride) {
        int si = 0;
#pragma unroll
        for (int k = 1; k < 7; ++k) si += (gi >= pa.s[k].g0);
        const PSeg sg = pa.s[si];
        const long i = gi - sg.g0;
        const int kq = 1 << sg.kshift;
        const int p = (int)(i >> sg.kshift);
        const int kk = ((int)i & (kq - 1)) << 2;
        const int o = ((p >> 6) << 4) | (p & 15);
        const int q = (p >> 4) & 3;
        const long r = (long)q * sg.H + o;
        const float4 v = *(const float4*)(sg.src + (r << (sg.kshift + 2)) + kk);
        u16x4 wv; wv.x = f2bf(v.x); wv.y = f2bf(v.y); wv.z = f2bf(v.z); wv.w = f2bf(v.w);
        *(u16x4*)(sg.dst + (long)p * sg.dstld + sg.dstcol + kk) = wv;
    }
}

// ---------------- merged combined+permuted biases (4 levels, 7680 elems)
__global__ __launch_bounds__(256) void bias_all(
    const float* __restrict__ bih1, const float* __restrict__ bhh1,
    const float* __restrict__ bih2, const float* __restrict__ bhh2,
    const float* __restrict__ bih3, const float* __restrict__ bhh3,
    const float* __restrict__ bih4, const float* __restrict__ bhh4,
    float* __restrict__ bs1, float* __restrict__ bs2,
    float* __restrict__ bs3, float* __restrict__ bs4)
{
    const int i = blockIdx.x * 256 + threadIdx.x;
    const float *bih, *bhh; float* dst; int H, j;
    if (i < 4096)      { bih = bih1; bhh = bhh1; dst = bs1; H = 1024; j = i; }
    else if (i < 6144) { bih = bih2; bhh = bhh2; dst = bs2; H = 512;  j = i - 4096; }
    else if (i < 7168) { bih = bih3; bhh = bhh3; dst = bs3; H = 256;  j = i - 6144; }
    else               { bih = bih4; bhh = bhh4; dst = bs4; H = 128;  j = i - 7168; }
    const int o = ((j >> 6) << 4) | (j & 15);
    const int q = (j >> 4) & 3;
    dst[j] = bih[q * H + o] + bhh[q * H + o];
}

// ---------------- 256x256 8-phase fused GEMM+LSTM-cell
#define QUAD(S, NS, BF)                                                                     \
    { _Pragma("unroll") for (int mi = 0; mi < 4; ++mi) {                                    \
        _Pragma("unroll") for (int ni = 0; ni < 2; ++ni) {                                  \
            acc[(S)*4+mi][(NS)*2+ni] = __builtin_amdgcn_mfma_f32_16x16x32_bf16(             \
                aF[mi][0], BF[ni][0], acc[(S)*4+mi][(NS)*2+ni], 0, 0, 0);                   \
            acc[(S)*4+mi][(NS)*2+ni] = __builtin_amdgcn_mfma_f32_16x16x32_bf16(             \
                aF[mi][1], BF[ni][1], acc[(S)*4+mi][(NS)*2+ni], 0, 0, 0);                   \
    } } }

#define GLL(gsrc, loff) __builtin_amdgcn_global_load_lds(                                   \
    (const AS1 void*)(gsrc), (AS3 void*)(lds + (loff)), 16, 0, 0)

#define FENCE asm volatile("" ::: "memory")

template<bool HAS_CIN, bool LAST>
__global__ __launch_bounds__(512, 2) void gemm8(
    const unsigned short* __restrict__ A, const unsigned short* __restrict__ W, const int K,
    const float* __restrict__ bsum, const float* __restrict__ Cin,
    float* __restrict__ Hout, float* __restrict__ Cout, const int H)
{
    __shared__ __align__(16) char lds[131072];
    const int t = threadIdx.x;
    const int w = t >> 6, l = t & 63;
    const int wr = w >> 2, wc = w & 3;                 // 2 x 4 wave grid

    // T1: bijective XCD swizzle (nwg is always a multiple of 8 here); bx-major
    const int GX = gridDim.x, GY = gridDim.y;
    const int nwg = GX * GY;
    const int bid = (int)blockIdx.y * GX + (int)blockIdx.x;
    const int swz = (bid & 7) * (nwg >> 3) + (bid >> 3);
    const int m0 = (swz / GY) * 256, n0 = (swz % GY) * 256;

    const int colsw = ((l & 7) ^ (l >> 3)) * 8;        // swizzled source col granule
    const size_t k128 = (size_t)128 * K;
    const size_t aoff0 = (size_t)(m0 + w * 16 + (l >> 3)) * K + colsw;
    const size_t aoff1 = aoff0 + (size_t)8 * K;
    const size_t boff0 = (size_t)(n0 + w * 16 + (l >> 3)) * K + colsw;
    const size_t boff1 = boff0 + (size_t)8 * K;
    const int sd0 = w * 2048 + l * 16;                 // LDS byte dest (within region)
    const int sd1 = sd0 + 1024;

    const int lr128 = (l & 15) * 128;
    const int sw0 = (((l >> 4)    ) ^ (l & 7)) * 16;   // swizzled ds_read granules
    const int sw1 = (((l >> 4) + 4) ^ (l & 7)) * 16;

    f32x4 acc[8][4];
#pragma unroll
    for (int i = 0; i < 8; ++i)
#pragma unroll
        for (int j = 0; j < 4; ++j) acc[i][j] = (f32x4){0.f, 0.f, 0.f, 0.f};

    const int NT = K >> 6;

    // ---- prologue: tile0 all 4 halves; tile1 {B-h0, B-h1, A-h0}
    GLL(A + aoff0, sd0);                      GLL(A + aoff1, sd1);
    GLL(A + aoff0 + k128, 16384 + sd0);       GLL(A + aoff1 + k128, 16384 + sd1);
    GLL(W + boff0, 32768 + sd0);              GLL(W + boff1, 32768 + sd1);
    GLL(W + boff0 + k128, 49152 + sd0);       GLL(W + boff1 + k128, 49152 + sd1);
    GLL(W + boff0 + 64, 98304 + sd0);         GLL(W + boff1 + 64, 98304 + sd1);
    GLL(W + boff0 + k128 + 64, 114688 + sd0); GLL(W + boff1 + k128 + 64, 114688 + sd1);
    GLL(A + aoff0 + 64, 65536 + sd0);         GLL(A + aoff1 + 64, 65536 + sd1);
    asm volatile("s_waitcnt vmcnt(6)" ::: "memory");
    __builtin_amdgcn_s_barrier();
    FENCE;

    bf16x8 aF[4][2], bF0[2][2], bF1[2][2];

    for (int tt = 0; tt < NT; ++tt) {
        const int q = tt & 1, qn = q ^ 1;
        const int rbA = (q << 16) + (wr << 14) + lr128;
        const int rbB = (q << 16) + 32768 + wc * 8192 + lr128;
        const size_t ko1 = (size_t)(tt + 1) * 64;
        const size_t ko2 = (size_t)(tt + 2) * 64;
        const bool st1 = (tt + 1 < NT), st2 = (tt + 2 < NT);

        // ---- P1: ds_read A-lo(8)+B-lo(4); stage A-h1(t+1); MFMA Q(0,0)
#pragma unroll
        for (int mi = 0; mi < 4; ++mi) {
            aF[mi][0] = *(const bf16x8*)(lds + rbA + mi * 2048 + sw0);
            aF[mi][1] = *(const bf16x8*)(lds + rbA + mi * 2048 + sw1);
        }
#pragma unroll
        for (int ni = 0; ni < 2; ++ni) {
            bF0[ni][0] = *(const bf16x8*)(lds + rbB + ni * 2048 + sw0);
            bF0[ni][1] = *(const bf16x8*)(lds + rbB + ni * 2048 + sw1);
        }
        if (st1) {
            GLL(A + aoff0 + k128 + ko1, (qn << 16) + 16384 + sd0);
            GLL(A + aoff1 + k128 + ko1, (qn << 16) + 16384 + sd1);
        }
        __builtin_amdgcn_s_barrier();
        FENCE;
        __builtin_amdgcn_s_setprio(1);
        QUAD(0, 0, bF0);
        __builtin_amdgcn_s_setprio(0);
        __builtin_amdgcn_s_barrier();
        FENCE;

        // ---- P2: ds_read B-hi(4); stage B-h0(t+2); MFMA Q(0,1)
#pragma unroll
        for (int ni = 0; ni < 2; ++ni) {
            bF1[ni][0] = *(const bf16x8*)(lds + rbB + 4096 + ni * 2048 + sw0);
            bF1[ni][1] = *(const bf16x8*)(lds + rbB + 4096 + ni * 2048 + sw1);
        }
        if (st2) {
            GLL(W + boff0 + ko2, (q << 16) + 32768 + sd0);
            GLL(W + boff1 + ko2, (q << 16) + 32768 + sd1);
        }
        __builtin_amdgcn_s_barrier();
        FENCE;
        __builtin_amdgcn_s_setprio(1);
        QUAD(0, 1, bF1);
        __builtin_amdgcn_s_setprio(0);
        __builtin_amdgcn_s_barrier();
        FENCE;

        // ---- P3: ds_read A-hi(8); stage B-h1(t+2); MFMA Q(1,1)
#pragma unroll
        for (int mi = 0; mi < 4; ++mi) {
            aF[mi][0] = *(const bf16x8*)(lds + rbA + 8192 + mi * 2048 + sw0);
            aF[mi][1] = *(const bf16x8*)(lds + rbA + 8192 + mi * 2048 + sw1);
        }
        if (st2) {
            GLL(W + boff0 + k128 + ko2, (q << 16) + 49152 + sd0);
            GLL(W + boff1 + k128 + ko2, (q << 16) + 49152 + sd1);
        }
        __builtin_amdgcn_s_barrier();
        FENCE;
        __builtin_amdgcn_s_setprio(1);
        QUAD(1, 1, bF1);
        __builtin_amdgcn_s_setprio(0);
        __builtin_amdgcn_s_barrier();
        FENCE;

        // ---- P4: stage A-h0(t+2); counted vmcnt; MFMA Q(1,0)
        if (st2) {
            GLL(A + aoff0 + ko2, (q << 16) + sd0);
            GLL(A + aoff1 + ko2, (q << 16) + sd1);
        }
        if (tt < NT - 2) { asm volatile("s_waitcnt vmcnt(6)" ::: "memory"); }
        else             { asm volatile("s_waitcnt vmcnt(0)" ::: "memory"); }
        __builtin_amdgcn_s_barrier();
        FENCE;
        __builtin_amdgcn_s_setprio(1);
        QUAD(1, 0, bF0);
        __builtin_amdgcn_s_setprio(0);
        __builtin_amdgcn_s_barrier();
        FENCE;
    }

    // ---- fused LSTM-cell epilogue
    const int ocol = (n0 >> 6) * 16 + wc * 16 + (l & 15);
    const int bb = n0 + wc * 64 + (l & 15);
    const float b0 = bsum[bb], b1 = bsum[bb + 16], b2 = bsum[bb + 32], b3 = bsum[bb + 48];
    const int mrow0 = m0 + wr * 128 + (l >> 4) * 4;
#pragma unroll
    for (int mi = 0; mi < 8; ++mi)
#pragma unroll
        for (int j = 0; j < 4; ++j) {
            const size_t m = (size_t)(mrow0 + mi * 16 + j);
            const float gi = acc[mi][0][j] + b0;
            const float gf = acc[mi][1][j] + b1;
            const float gg = acc[mi][2][j] + b2;
            const float go = acc[mi][3][j] + b3;
            float c2 = sigm(gi) * tanh_(gg);
            if (HAS_CIN) c2 += sigm(gf) * Cin[m * H + ocol];
            const float h2 = sigm(go) * tanh_(c2);
            Hout[m * H + ocol] = h2;
            if (!LAST) Cout[m * H + ocol] = c2;
        }
}

// ---------------- conv1d(k=3,pad=1)+softmax for h AND c in one launch
// blocks [0,nrows): h -> bf16 strided dst; [nrows,2*nrows): c -> f32 dst
template<int L>
__global__ __launch_bounds__(256) void conv_dual(
    const float* __restrict__ Hin, const float* __restrict__ Cin,
    const float* __restrict__ w3h, const float* __restrict__ w3c,
    unsigned short* __restrict__ Yb, int ldYb, float* __restrict__ cbuf)
{
    __shared__ float xs[L + 2];
    __shared__ float red[8];
    const int nrows = gridDim.x >> 1;
    const bool isC = (int)blockIdx.x >= nrows;
    const int row = isC ? ((int)blockIdx.x - nrows) : (int)blockIdx.x;
    const float* Xs = isC ? Cin : Hin;
    const float* w3 = isC ? w3c : w3h;
    const int t = threadIdx.x;
    const size_t base = (size_t)row * L;
    const float w0 = w3[0], w1 = w3[1], w2 = w3[2];
    if (t == 0) { xs[0] = 0.f; xs[L + 1] = 0.f; }
    for (int i = t; i < L; i += 256) xs[i + 1] = Xs[base + i];
    __syncthreads();
    constexpr int E = L / 256;
    float y[E];
    float vmax = -3.4e38f;
#pragma unroll
    for (int i = 0; i < E; ++i) {
        const int c = t + i * 256;
        y[i] = w0 * xs[c] + w1 * xs[c + 1] + w2 * xs[c + 2];
        vmax = fmaxf(vmax, y[i]);
    }
#pragma unroll
    for (int off = 32; off >= 1; off >>= 1) vmax = fmaxf(vmax, __shfl_xor(vmax, off));
    if ((t & 63) == 0) red[t >> 6] = vmax;
    __syncthreads();
    vmax = fmaxf(fmaxf(red[0], red[1]), fmaxf(red[2], red[3]));
    float s = 0.f;
#pragma unroll
    for (int i = 0; i < E; ++i) { y[i] = __expf(y[i] - vmax); s += y[i]; }
#pragma unroll
    for (int off = 32; off >= 1; off >>= 1) s += __shfl_xor(s, off);
    if ((t & 63) == 0) red[4 + (t >> 6)] = s;
    __syncthreads();
    const float inv = 1.f / (red[4] + red[5] + red[6] + red[7]);
#pragma unroll
    for (int i = 0; i < E; ++i) {
        const int c = t + i * 256;
        const float v = y[i] * inv;
        if (isC) cbuf[base + c] = v;
        else     Yb[(size_t)row * ldYb + c] = f2bf(v);
    }
}

extern "C" void kernel_launch(void* const* d_in, const int* in_sizes, int n_in,
                              void* d_out, int out_size, void* d_ws, size_t ws_size,
                              hipStream_t stream)
{
    (void)in_sizes; (void)n_in; (void)out_size; (void)ws_size;
    const float* spec  = (const float*)d_in[0];
    const float* Wih1  = (const float*)d_in[1];
    const float* Whh1  = (const float*)d_in[2];
    const float* bih1  = (const float*)d_in[3];
    const float* bhh1  = (const float*)d_in[4];
    const float* Wih2  = (const float*)d_in[5];
    const float* Whh2  = (const float*)d_in[6];
    const float* bih2  = (const float*)d_in[7];
    const float* bhh2  = (const float*)d_in[8];
    const float* Wih3  = (const float*)d_in[9];
    const float* Whh3  = (const float*)d_in[10];
    const float* bih3  = (const float*)d_in[11];
    const float* bhh3  = (const float*)d_in[12];
    const float* Wih4  = (const float*)d_in[13];
    const float* bih4  = (const float*)d_in[15];
    const float* bhh4  = (const float*)d_in[16];
    const float* w2_1h = (const float*)d_in[17];
    const float* w2_1c = (const float*)d_in[18];
    const float* w3_2h = (const float*)d_in[19];
    const float* w3_2c = (const float*)d_in[20];
    const float* w4_3h = (const float*)d_in[21];
    const float* w4_3c = (const float*)d_in[22];

    char* ws = (char*)d_ws;
    float*          h   = (float*)(ws + 0);                         // 16 MiB
    float*          c   = (float*)(ws + (size_t)16777216);          // 16 MiB
    float*          cb  = (float*)(ws + (size_t)33554432);          // 16 MiB
    unsigned short* sB  = (unsigned short*)(ws + (size_t)50331648); // 16 MiB (spec bf16, L4 A)
    unsigned short* X   = (unsigned short*)(ws + (size_t)67108864); // 24 MiB (A_cat3 -> A_cat1)
    unsigned short* Y   = (unsigned short*)(ws + (size_t)92274688); // 24 MiB (A_cat2)
    unsigned short* Wc1 = (unsigned short*)(ws + (size_t)117440512);// 24 MiB
    unsigned short* Wc2 = (unsigned short*)(ws + (size_t)142606336);//  6 MiB
    unsigned short* Wc3 = (unsigned short*)(ws + (size_t)148897792);// 1.5 MiB
    unsigned short* W4  = (unsigned short*)(ws + (size_t)150470656);// 0.25 MiB
    float*          bs1 = (float*)(ws + (size_t)150732800);
    float*          bs2 = bs1 + 4096;
    float*          bs3 = bs2 + 4096;
    float*          bs4 = bs3 + 4096;

    // ---- conversions (Whh4 unused: level-4 h_in == 0)
    cvt_spec3<<<2048, 256, 0, stream>>>(spec, sB, X, Y, 2097152);
    PArgs pa;
    pa.s[0] = { Wih1, Wc1,       0, 1024, 9, 3072,    0 };
    pa.s[1] = { Whh1, Wc1, 2097152, 1024, 8, 3072, 2048 };
    pa.s[2] = { Wih2, Wc2, 3145728,  512, 8, 1536,    0 };
    pa.s[3] = { Whh2, Wc2, 3670016,  512, 7, 1536, 1024 };
    pa.s[4] = { Wih3, Wc3, 3932160,  256, 7,  768,    0 };
    pa.s[5] = { Whh3, Wc3, 4063232,  256, 6,  768,  512 };
    pa.s[6] = { Wih4, W4,  4128768,  128, 6,  256,    0 };
    pa.total = 4161536;
    cvt_permW_all<<<2048, 256, 0, stream>>>(pa);
    bias_all<<<30, 256, 0, stream>>>(bih1, bhh1, bih2, bhh2, bih3, bhh3, bih4, bhh4,
                                     bs1, bs2, bs3, bs4);

    // ---- Level 4: M=32768, N=512 (H=128), K=256
    gemm8<false, false><<<dim3(128, 2), 512, 0, stream>>>(sB, W4, 256, bs4, nullptr, h, c, 128);
    conv_dual<256><<<32768, 256, 0, stream>>>(h, c, w4_3h, w4_3c, X + 512, 768, cb);

    // ---- Level 3: M=16384, N=1024 (H=256), K=768
    gemm8<true, false><<<dim3(64, 4), 512, 0, stream>>>(X, Wc3, 768, bs3, cb, h, c, 256);
    cvt_specA<<<2048, 256, 0, stream>>>(spec, X, 2097152);     // A_cat1 spec part (X@768 free)
    conv_dual<512><<<16384, 256, 0, stream>>>(h, c, w3_2h, w3_2c, Y + 1024, 1536, cb);

    // ---- Level 2: M=8192, N=2048 (H=512), K=1536
    gemm8<true, false><<<dim3(32, 8), 512, 0, stream>>>(Y, Wc2, 1536, bs2, cb, h, c, 512);
    conv_dual<1024><<<8192, 256, 0, stream>>>(h, c, w2_1h, w2_1c, X + 2048, 3072, cb);

    // ---- Level 1: M=4096, N=4096 (H=1024), K=3072; h1 -> d_out (f32)
    gemm8<true, true><<<dim3(16, 16), 512, 0, stream>>>(X, Wc1, 3072, bs1, cb, (float*)d_out, nullptr, 1024);
}